// Round 10
// baseline (114.243 us; speedup 1.0000x reference)
//
#include <hip/hip_runtime.h>
#include <math.h>

typedef _Float16 f16x2 __attribute__((ext_vector_type(2)));

namespace {
constexpr int DIN = 36, DOUT = 34;
constexpr int TDD = 2, TE = 8, TF = 8;       // site tile (d,e,f) = (2,8,8) = 128 sites
constexpr int RD = 4, RE = 10, RF = 10;      // staged region rows
constexpr int NROWS = RD*RE*RF;              // 400 rows
constexpr int ROWW  = 38;                    // dwords/row (36 data + 2 pad) = 152 B; odd 8B-bank stride (19)
constexpr int NCHUNK = NROWS*9;              // 3600 16-B source chunks
constexpr int NBD = 17, NBE = 5, NBF = 5;
constexpr int BLOCKS_PER_B = NBD*NBE*NBF;    // 425
constexpr int NBLOCKS = 8*BLOCKS_PER_B;      // 3400 = 8 XCDs x 425
constexpr int NT = 512;
constexpr int SITER = (NCHUNK + NT - 1)/NT;  // 8
constexpr int D3 = DIN*DIN*DIN, D2 = DIN*DIN;
}

__device__ __forceinline__ unsigned div9u(unsigned n)   { return __umulhi(n, 0x38E38E39u) >> 1; }
__device__ __forceinline__ unsigned div100u(unsigned n) { return __umulhi(n, 0x51EB851Fu) >> 5; }
__device__ __forceinline__ unsigned div10u(unsigned n)  { return __umulhi(n, 0x66666667u) >> 2; }

__device__ __forceinline__ float h2f(f16x2 h) { union { f16x2 h; float f; } u; u.h = h; return u.f; }
__device__ __forceinline__ f16x2 f2h(float f) { union { float f; f16x2 h; } u; u.f = f; return u.h; }
__device__ __forceinline__ unsigned pack2(float a, float b) {
    union { f16x2 h; unsigned u; } u_; u_.h = f16x2{(_Float16)a, (_Float16)b}; return u_.u;
}

#if __has_builtin(__builtin_amdgcn_fdot2)
__device__ __forceinline__ float dot2(f16x2 a, f16x2 b, float c) {
    return __builtin_amdgcn_fdot2(a, b, c, false);
}
#else
__device__ __forceinline__ float dot2(f16x2 a, f16x2 b, float c) {
    return fmaf((float)a.x, (float)b.x, fmaf((float)a.y, (float)b.y, c));
}
#endif

// Coalesced stage of both channels, interleaved (xr,xi) half2 per dword.
// No clamping needed: tile origins chosen so the whole region is in-bounds.
__device__ __forceinline__ void stage(const float* __restrict__ xr, const float* __restrict__ xi,
                                      unsigned* __restrict__ s_xu, int t, unsigned g0off)
{
    #pragma unroll
    for (int it = 0; it < SITER; ++it) {
        const int C = it*NT + t;
        if (C < NCHUNK) {
            const unsigned row = div9u((unsigned)C);
            const unsigned c   = (unsigned)C - row*9u;
            const unsigned rd  = div100u(row);
            const unsigned rem = row - rd*100u;
            const unsigned re  = div10u(rem);
            const unsigned rf  = rem - re*10u;
            const unsigned goff = g0off + rd*D3 + re*D2 + rf*DIN + c*4u;
            const float4 vr = *reinterpret_cast<const float4*>(xr + goff);
            const float4 vi = *reinterpret_cast<const float4*>(xi + goff);
            unsigned* dst = s_xu + row*ROWW + c*4;
            uint2 lo, hi;
            lo.x = pack2(vr.x, vi.x); lo.y = pack2(vr.y, vi.y);
            hi.x = pack2(vr.z, vi.z); hi.y = pack2(vr.w, vi.w);
            *reinterpret_cast<uint2*>(dst)     = lo;    // 8B-aligned writes
            *reinterpret_cast<uint2*>(dst + 2) = hi;
        }
    }
}

// One w-group's conv + epilogue. All register indices compile-time; b64 LDS reads.
template<int NW, int W0>
__device__ __forceinline__ float conv_group(const unsigned* __restrict__ s_xu,
                                            const float4* __restrict__ s_wA,
                                            const float4* __restrict__ s_wB,
                                            int td, int e, int f,
                                            const float* __restrict__ s_hw,
                                            float c_br, float c_bi, float hinit)
{
    constexpr int NL = NW/2 + 1;                 // b64 loads per row-window
    float yr[NW], yi[NW];
    #pragma unroll
    for (int w = 0; w < NW; ++w) { yr[w] = c_br; yi[w] = c_bi; }

    const int abase = (td*(RE*RF) + e*RF + f)*ROWW + W0;   // even dword -> 8B aligned

    #pragma unroll 1
    for (int i = 0; i < 3; ++i)
    #pragma unroll 1
    for (int j = 0; j < 3; ++j)
    {
        const unsigned* sp = s_xu + abase + (i*(RE*RF) + j*RF)*ROWW;
        const int tapb = (i*3 + j)*3;
        #pragma unroll
        for (int k = 0; k < 3; ++k)              // k*ROWW*4 folds into ds offsets
        {
            uint2 q[NL];
            #pragma unroll
            for (int m = 0; m < NL; ++m)
                q[m] = *reinterpret_cast<const uint2*>(sp + k*ROWW + 2*m);
            const f16x2* win = reinterpret_cast<const f16x2*>(q);

            const float4 wa = s_wA[tapb + k];    // uniform broadcast reads
            const float4 wb = s_wB[tapb + k];
            #pragma unroll
            for (int l = 0; l < 3; ++l) {
                const f16x2 wal = f2h(l==0 ? wa.x : l==1 ? wa.y : wa.z);  // (wr, -wi)
                const f16x2 wbl = f2h(l==0 ? wb.x : l==1 ? wb.y : wb.z);  // (wi,  wr)
                #pragma unroll
                for (int w = 0; w < NW; ++w) {
                    yr[w] = dot2(win[w+l], wal, yr[w]);
                    yi[w] = dot2(win[w+l], wbl, yi[w]);
                }
            }
        }
    }

    float h = hinit;
    #pragma unroll
    for (int w = 0; w < NW; ++w) {
        const float a = fmaxf(yr[w], 0.f);
        const float c = fmaxf(yi[w], 0.f);
        const float m = sqrtf(fmaf(a, a, fmaf(c, c, 1e-12f)));
        h = fmaf(m, s_hw[W0 + w], h);
    }
    return h;
}

__global__ __launch_bounds__(NT)
void lasl_kernel(const float* __restrict__ xr, const float* __restrict__ xi,
                 const float* __restrict__ wr, const float* __restrict__ wi,
                 const float* __restrict__ br, const float* __restrict__ bi,
                 const float* __restrict__ hw, const float* __restrict__ hb,
                 float* __restrict__ out)
{
    __shared__ unsigned s_xu[NROWS*ROWW];        // 60.8 KB
    __shared__ float4 s_wA[27], s_wB[27];
    __shared__ float  s_hw[DOUT], s_scal[3];

    const int t = threadIdx.x;
    if (t < 27) {
        const float w0r = wr[3*t], w1r = wr[3*t+1], w2r = wr[3*t+2];
        const float w0i = wi[3*t], w1i = wi[3*t+1], w2i = wi[3*t+2];
        s_wA[t] = make_float4(h2f(f16x2{(_Float16)w0r, (_Float16)(-w0i)}),
                              h2f(f16x2{(_Float16)w1r, (_Float16)(-w1i)}),
                              h2f(f16x2{(_Float16)w2r, (_Float16)(-w2i)}), 0.f);
        s_wB[t] = make_float4(h2f(f16x2{(_Float16)w0i, (_Float16)w0r}),
                              h2f(f16x2{(_Float16)w1i, (_Float16)w1r}),
                              h2f(f16x2{(_Float16)w2i, (_Float16)w2r}), 0.f);
    } else if (t >= 32 && t < 32 + DOUT) {
        s_hw[t-32] = hw[t-32];
    } else if (t == 96) { s_scal[0] = br[0]; s_scal[1] = bi[0]; s_scal[2] = hb[0]; }

    // batch-per-XCD bijective swizzle: 3400 = 8 * 425
    const int bid = blockIdx.x;
    const int b   = bid & 7;
    int rem = bid >> 3;                          // 0..424
    const int d0 = (rem / 25) * TDD;  rem %= 25; // exact: 17*2 = 34
    const int e0 = min((rem / 5) * TE, DOUT - TE);  // overlap tiles: {0,8,16,24,26}
    const int f0 = min((rem % 5) * TF, DOUT - TF);

    const float* xrb = xr + (size_t)b * (size_t)(DIN*D3);
    const float* xib = xi + (size_t)b * (size_t)(DIN*D3);
    const unsigned g0off = (unsigned)((d0*DIN + e0)*DIN + f0)*DIN;

    stage(xrb, xib, s_xu, t, g0off);
    __syncthreads();

    const int f  = t & 7;                        // site within tile
    const int e  = (t >> 3) & 7;
    const int g  = (t >> 6) & 3;                 // wave-uniform w-group (4 groups)
    const int td = t >> 8;                       // wave-uniform d-sub

    const float c_br = s_scal[0], c_bi = s_scal[1];
    const float hini = (g == 0) ? s_scal[2] : 0.f;   // hb counted once

    float hp;
    if      (g == 0) hp = conv_group<10, 0>(s_xu, s_wA, s_wB, td, e, f, s_hw, c_br, c_bi, hini);
    else if (g == 1) hp = conv_group< 8,10>(s_xu, s_wA, s_wB, td, e, f, s_hw, c_br, c_bi, hini);
    else if (g == 2) hp = conv_group< 8,18>(s_xu, s_wA, s_wB, td, e, f, s_hw, c_br, c_bi, hini);
    else             hp = conv_group< 8,26>(s_xu, s_wA, s_wB, td, e, f, s_hw, c_br, c_bi, hini);

    // combine the 4 w-group partials (one per wave, same td) through LDS
    __syncthreads();                             // all s_xu reads done
    float* s_red = reinterpret_cast<float*>(s_xu);
    s_red[t] = hp;
    __syncthreads();

    if (g == 0) {
        const int eg = e0 + e, fg = f0 + f;      // always < 34 (overlap tiling)
        const float htot = hp + s_red[t + 64] + s_red[t + 128] + s_red[t + 192];
        out[(((size_t)b*DOUT + (d0 + td))*DOUT + eg)*DOUT + fg] = 1.f / (1.f + __expf(-htot));
    }
}

extern "C" void kernel_launch(void* const* d_in, const int* in_sizes, int n_in,
                              void* d_out, int out_size, void* d_ws, size_t ws_size,
                              hipStream_t stream)
{
    const float* xr = (const float*)d_in[0];
    const float* xi = (const float*)d_in[1];
    const float* wr = (const float*)d_in[2];
    const float* wi = (const float*)d_in[3];
    const float* br = (const float*)d_in[4];
    const float* bi = (const float*)d_in[5];
    const float* hw = (const float*)d_in[6];
    const float* hb = (const float*)d_in[7];
    float* out = (float*)d_out;

    lasl_kernel<<<NBLOCKS, NT, 0, stream>>>(xr, xi, wr, wi, br, bi, hw, hb, out);
}